// Round 7
// baseline (415.230 us; speedup 1.0000x reference)
//
#include <hip/hip_runtime.h>
#include <hip/hip_bf16.h>

// TaylorMap, symmetric-packed quadratic form, UNIFORM-9 PAIR STREAM + K-SPLIT.
// x_{t+1} = x_t + W0 + W1^T x + sum_{i<=j} x_i x_j (W2[i,j,:]+W2[j,i,:]) , 7 steps.
// Pair (p,127-p) costs exactly 9 MFMA slices (sl(p)+sl(127-p)=7) -> uniform body.
// R6 landed 330 us, MfmaUtil 39%, nothing saturated -> latency-bound at
// 2 waves/SIMD (grid 256 = 1 block/CU). R7: K-split the pair stream across a
// wave pair (g=0: pairs 0..31, g=1: pairs 32..63 + linear row), BT=32,
// grid=512 blocks -> 2 blocks/CU -> 4 waves/SIMD. Inner loop and register
// shape are IDENTICAL to R6 (bfrag[8]=32, abuf[2][9]=72, 128 arch, no spill);
// one LDS merge per step (stride-17 scratch, conflict-free) joins the halves.
// A layout unchanged from R6: slice 9p for pair p, linear @576, pad @584.

#define DSTATE 128
#define BATCH  16384
#define NSTEPS 7
#define BT     32           // batch cols per block (R7: halved, 2 blocks/CU)
#define NSL    585          // slices per d-tile: 64*9 pair + 8 linear + 1 pad

typedef __attribute__((ext_vector_type(8)))  short  short8;   // 8 bf16 = 4 VGPRs
typedef __attribute__((ext_vector_type(16))) float  f32x16;   // MFMA 32x32 C/D

__device__ __forceinline__ unsigned short f2bf(float f){
    unsigned int u = __float_as_uint(f);
    u += 0x7fff + ((u >> 16) & 1);          // RNE
    return (unsigned short)(u >> 16);
}

// Pack symmetric-folded W into bf16 MFMA-A fragments, uniform-9 pair stream.
// Pair p occupies positions 9p..9p+8: first 8-(p>>4) slices are row p
// (j-blocks p>>4..7), remaining 1+(p>>4) are row 127-p (j-blocks 7-(p>>4)..7).
// Fragment layout: A[m][k], m=lane&31 -> d=32t+m, k=(lane>>5)*8+e -> j=16*s+k.
__global__ void prep_kernel(const float* __restrict__ W, short8* __restrict__ A){
    int gid = blockIdx.x * 256 + threadIdx.x;
    const int ntotal = 4 * 130 * 8 * 64;
    if (gid >= ntotal) return;
    int lane = gid & 63; int r = gid >> 6;
    int s = r & 7;  r >>= 3;
    int row = r % 130;
    int t   = r / 130;
    int d  = t * 32 + (lane & 31);
    int kb = (lane >> 5) * 8;
    int dst;
    bool zero = false;
    if (row < 64){
        int sl = row >> 4;
        if (s < sl) return;                    // row uses j-blocks sl..7
        dst = t * NSL + 9 * row + (s - sl);
    } else if (row < 128){
        int p  = 127 - row;                    // partner pair index
        int sl = row >> 4;
        if (s < sl) return;
        int ca = 8 - (p >> 4);                 // partner-row slice count
        dst = t * NSL + 9 * p + ca + (s - sl);
    } else if (row == 128){
        dst = t * NSL + 576 + s;               // linear (W1) row
    } else {
        if (s) return;                         // zero pad slice (prefetch target)
        dst = t * NSL + 584;
        zero = true;
    }
    union { short8 v; unsigned short u[8]; } fr;
#pragma unroll
    for (int e = 0; e < 8; ++e){
        int j = s * 16 + kb + e;
        float v;
        if (zero) v = 0.0f;
        else if (row < 128){
            if      (j < row)  v = 0.0f;
            else if (j == row) v = W[(129 + 128 * row + j) * 128 + d];
            else               v = W[(129 + 128 * row + j) * 128 + d]
                                 + W[(129 + 128 * j + row) * 128 + d];
        } else {
            v = W[(1 + j) * 128 + d];
        }
        fr.u[e] = f2bf(v);
    }
    A[(size_t)dst * 64 + lane] = fr.v;
}

__global__ __launch_bounds__(512, 2)
void taylor_kernel(const float* __restrict__ X, const float* __restrict__ W,
                   const float* __restrict__ tini, const float* __restrict__ lini,
                   const short8* __restrict__ A, float* __restrict__ out)
{
    __shared__ float x_lds[DSTATE * BT];       // fp32 master state, [d][b] (16 KB)
    __shared__ float w0_lds[DSTATE];
    __shared__ float sc_lds[4 * 64 * 17];      // K-split merge scratch (17.4 KB)

    const int tid  = threadIdx.x;
    const int lane = tid & 63;
    const int w    = tid >> 6;
    const int t    = w & 3;                    // d-tile (32 dims)
    const int g    = w >> 2;                   // K-half (pair blocks 0-1 / 2-3+lin)
    const int ln   = lane & 31;
    const int hi   = lane >> 5;
    const int col  = ln;                       // this lane's batch column (0..31)
    const int b0   = blockIdx.x * BT;

    // ---- init x0 = [X | t_init | l_init] ----
#pragma unroll
    for (int it = 0; it < 8; ++it){
        int entry = tid + it * 512;            // entry = b*128 + d
        int b = entry >> 7, d = entry & 127;
        float v;
        if      (d < 120) v = X[(b0 + b) * 120 + d];
        else if (d < 124) v = tini[d - 120];
        else              v = lini[d - 124];
        x_lds[d * BT + b] = v;
    }
    if (tid < DSTATE) w0_lds[tid] = W[tid];

    // wave's half-stream base: g0 -> slice 0, g1 -> slice 288 (pair 32)
    const short8* const Aw = A + ((size_t)t * NSL + (size_t)g * 288) * 64 + lane;

#pragma unroll 1
    for (int step = 0; step < NSTEPS; ++step){
        __syncthreads();                       // (A) x_lds stable for this step

        // ---- B fragments for own 32 cols (8 frags = 32 VGPRs) ----
        short8 bfrag[8];
#pragma unroll
        for (int s = 0; s < 8; ++s){
            union { short8 v; unsigned short u[8]; } fr;
#pragma unroll
            for (int e = 0; e < 8; ++e){
                int j = s * 16 + hi * 8 + e;
                fr.u[e] = f2bf(x_lds[j * BT + col]);
            }
            bfrag[s] = fr.v;
        }

        // ---- acc: g0 carries x_old + W0; g1 is a pure partial ----
        f32x16 acc;
        if (g == 0){
#pragma unroll
            for (int r = 0; r < 16; ++r){
                int d = 32 * t + (r & 3) + 8 * (r >> 2) + 4 * hi;
                acc[r] = x_lds[d * BT + col] + w0_lds[d];
            }
        } else {
#pragma unroll
            for (int r = 0; r < 16; ++r) acc[r] = 0.f;
        }

        // ---- pair loop: 2 compact rolled loops per wave, 9-slice prefetch ----
        const short8* ap = Aw;
        short8 abuf[2][9];
#pragma unroll
        for (int s = 0; s < 9; ++s) abuf[0][s] = ap[s * 64];
        ap += 9 * 64;

        // pair p = 16*BK+q: rows (p, 127-p); chains C_A=8-BK, C_B=1+BK.
        // Uniform 9-slice prefetch, no boundary conditional. g1's final
        // prefetch (pair 63) lands on linear row + pad -> abuf[0]. g0's
        // trailing prefetch reads pair 32 (unused, in-bounds).
#define PAIRS(BK)                                                               \
        _Pragma("unroll 2")                                                     \
        for (int q = 0; q < 16; ++q){                                           \
            const int cur = q & 1, nxt = cur ^ 1;                               \
            _Pragma("unroll")                                                   \
            for (int s = 0; s < 9; ++s) abuf[nxt][s] = ap[s * 64];              \
            ap += 9 * 64;                                                       \
            const int p = 16 * (BK) + q;                                        \
            float s0 = x_lds[p * BT + col];                                     \
            float s1 = x_lds[(127 - p) * BT + col];                             \
            f32x16 Y = {};                                                      \
            _Pragma("unroll")                                                   \
            for (int s = 0; s < 8 - (BK); ++s)                                  \
                Y = __builtin_amdgcn_mfma_f32_32x32x16_bf16(abuf[cur][s], bfrag[(BK) + s], Y, 0, 0, 0); \
            acc += s0 * Y;                                                      \
            f32x16 Z = {};                                                      \
            _Pragma("unroll")                                                   \
            for (int s = 0; s < 1 + (BK); ++s)                                  \
                Z = __builtin_amdgcn_mfma_f32_32x32x16_bf16(abuf[cur][8 - (BK) + s], bfrag[7 - (BK) + s], Z, 0, 0, 0); \
            acc += s1 * Z;                                                      \
        }

        if (g == 0){
            PAIRS(0) PAIRS(1)
        } else {
            PAIRS(2) PAIRS(3)
            // linear (W1) row, scale 1 (abuf[0] holds slices 576..583)
            f32x16 Y = {};
#pragma unroll
            for (int s = 0; s < 8; ++s)
                Y = __builtin_amdgcn_mfma_f32_32x32x16_bf16(abuf[0][s], bfrag[s], Y, 0, 0, 0);
            acc += Y;
            // publish g1 partial
#pragma unroll
            for (int r = 0; r < 16; ++r) sc_lds[(t * 64 + lane) * 17 + r] = acc[r];
        }
#undef PAIRS

        __syncthreads();                       // (B) x reads done + scratch visible
        if (g == 0){
#pragma unroll
            for (int r = 0; r < 16; ++r) acc[r] += sc_lds[(t * 64 + lane) * 17 + r];
            if (step < NSTEPS - 1){
#pragma unroll
                for (int r = 0; r < 16; ++r){
                    int d = 32 * t + (r & 3) + 8 * (r >> 2) + 4 * hi;
                    x_lds[d * BT + col] = acc[r];
                }
            } else if (t == 3 && hi == 0){
                // out dims 120..123 -> tile 3, regs 12..15 @ hi==0
                *(float4*)(out + (size_t)(b0 + col) * 4) =
                    make_float4(acc[12], acc[13], acc[14], acc[15]);
            }
        }
        // next iteration's barrier (A) orders g0's x_lds write against
        // g1's next bfrag build / scratch overwrite
    }
}

extern "C" void kernel_launch(void* const* d_in, const int* in_sizes, int n_in,
                              void* d_out, int out_size, void* d_ws, size_t ws_size,
                              hipStream_t stream)
{
    const float* X  = (const float*)d_in[0];
    const float* W  = (const float*)d_in[1];
    const float* ti = (const float*)d_in[2];
    const float* li = (const float*)d_in[3];
    float* out      = (float*)d_out;
    short8* A       = (short8*)d_ws;           // 4*585*64*16 B = 2.40 MB

    const int ntotal = 4 * 130 * 8 * 64;
    prep_kernel<<<(ntotal + 255) / 256, 256, 0, stream>>>(W, A);
    taylor_kernel<<<BATCH / BT, 512, 0, stream>>>(X, W, ti, li, A, out);
}

// Round 8
// 366.803 us; speedup vs baseline: 1.1320x; 1.1320x over previous
//
#include <hip/hip_runtime.h>
#include <hip/hip_bf16.h>

// TaylorMap, symmetric-packed quadratic form, uniform-9 pair stream,
// R8: 64 cols/wave (2 col-groups, B from LDS) + K-split wave pair.
// x_{t+1} = x_t + W0 + W1^T x + sum_{i<=j} x_i x_j (W2[i,j,:]+W2[j,i,:]) , 7 steps.
// R7 post-mortem: occupancy is register-locked at 2 waves/SIMD (~188 unified
// regs/wave); K-split alone can't help. R8 attacks within that budget:
//  - each A slice feeds TWO independent chains (col-groups) -> 4 chains/SIMD
//  - B fragments live in LDS (bpack, 16 KB) not registers
//  - chain C-operand = persistent zero16 (no per-chain accvgpr zero-inits)
//  - A stream read once per CU per step (2.34 MB vs R6's 4.68)
// LDS deliberately 82.5 KB: forces 1 block/CU so the compiler's LDS-derived
// occupancy target is 8 waves -> 256-reg cap (R3's 128-cap trap can't fire).

#define DSTATE 128
#define BATCH  16384
#define NSTEPS 7
#define BT     64
#define NSL    585          // slices per d-tile: 64*9 pair + 8 linear + 1 pad

typedef __attribute__((ext_vector_type(8)))  short  short8;   // 8 bf16 = 4 VGPRs
typedef __attribute__((ext_vector_type(16))) float  f32x16;   // MFMA 32x32 C/D

__device__ __forceinline__ unsigned short f2bf(float f){
    unsigned int u = __float_as_uint(f);
    u += 0x7fff + ((u >> 16) & 1);          // RNE
    return (unsigned short)(u >> 16);
}

// Pack symmetric-folded W into bf16 MFMA-A fragments, uniform-9 pair stream.
// Pair p at positions 9p..9p+8: first 8-(p>>4) slices are row p (j-blocks
// p>>4..7), remaining 1+(p>>4) are row 127-p (j-blocks 7-(p>>4)..7).
// Fragment layout: A[m][k], m=lane&31 -> d=32t+m, k=(lane>>5)*8+e -> j=16*s+k.
__global__ void prep_kernel(const float* __restrict__ W, short8* __restrict__ A){
    int gid = blockIdx.x * 256 + threadIdx.x;
    const int ntotal = 4 * 130 * 8 * 64;
    if (gid >= ntotal) return;
    int lane = gid & 63; int r = gid >> 6;
    int s = r & 7;  r >>= 3;
    int row = r % 130;
    int t   = r / 130;
    int d  = t * 32 + (lane & 31);
    int kb = (lane >> 5) * 8;
    int dst;
    bool zero = false;
    if (row < 64){
        int sl = row >> 4;
        if (s < sl) return;
        dst = t * NSL + 9 * row + (s - sl);
    } else if (row < 128){
        int p  = 127 - row;
        int sl = row >> 4;
        if (s < sl) return;
        int ca = 8 - (p >> 4);
        dst = t * NSL + 9 * p + ca + (s - sl);
    } else if (row == 128){
        dst = t * NSL + 576 + s;               // linear (W1) row
    } else {
        if (s) return;                         // zero pad slice
        dst = t * NSL + 584;
        zero = true;
    }
    union { short8 v; unsigned short u[8]; } fr;
#pragma unroll
    for (int e = 0; e < 8; ++e){
        int j = s * 16 + kb + e;
        float v;
        if (zero) v = 0.0f;
        else if (row < 128){
            if      (j < row)  v = 0.0f;
            else if (j == row) v = W[(129 + 128 * row + j) * 128 + d];
            else               v = W[(129 + 128 * row + j) * 128 + d]
                                 + W[(129 + 128 * j + row) * 128 + d];
        } else {
            v = W[(1 + j) * 128 + d];
        }
        fr.u[e] = f2bf(v);
    }
    A[(size_t)dst * 64 + lane] = fr.v;
}

__global__ __launch_bounds__(512)
void taylor_kernel(const float* __restrict__ X, const float* __restrict__ W,
                   const float* __restrict__ tini, const float* __restrict__ lini,
                   const short8* __restrict__ A, float* __restrict__ out)
{
    __shared__ float  x_lds[DSTATE * BT];      // fp32 master state [d][b], 32 KB
    __shared__ float  w0_lds[DSTATE];
    __shared__ short8 bpack[2 * 8 * 64];       // B frags, 2 groups x 8 slices, 16 KB
    __shared__ float  sc_lds[2][4 * 64 * 17];  // K-merge scratch, 34.8 KB

    const int tid  = threadIdx.x;
    const int lane = tid & 63;
    const int w    = tid >> 6;
    const int t    = w & 3;                    // d-tile
    const int g    = w >> 2;                   // K-half (pairs 0..31 / 32..63+lin)
    const int ln   = lane & 31;
    const int hi   = lane >> 5;
    const int b0   = blockIdx.x * BT;

    // ---- init x0 = [X | t_init | l_init] ----
#pragma unroll
    for (int it = 0; it < 16; ++it){
        int entry = tid + it * 512;            // entry = b*128 + d
        int b = entry >> 7, d = entry & 127;
        float v;
        if      (d < 120) v = X[(b0 + b) * 120 + d];
        else if (d < 124) v = tini[d - 120];
        else              v = lini[d - 124];
        x_lds[d * BT + b] = v;
    }
    if (tid < DSTATE) w0_lds[tid] = W[tid];

    // wave's half-stream base: g0 -> slice 0, g1 -> slice 288 (pair 32)
    const short8* const Aw = A + ((size_t)t * NSL + (size_t)g * 288) * 64 + lane;
    const f32x16 zero16 = {};                  // persistent zero C-operand

#pragma unroll 1
    for (int step = 0; step < NSTEPS; ++step){
        __syncthreads();                       // (A) x_lds stable

        // ---- prime A prefetch early (independent of LDS) ----
        const short8* ap = Aw;
        short8 abuf[2][9];
#pragma unroll
        for (int s = 0; s < 9; ++s) abuf[0][s] = ap[s * 64];
        ap += 9 * 64;

        // ---- build bpack (1024 frags, 2 per thread) while loads fly ----
#pragma unroll
        for (int f0 = 0; f0 < 2; ++f0){
            int f  = tid + f0 * 512;
            int gg = f >> 9, s = (f >> 6) & 7, l = f & 63;
            int c  = gg * 32 + (l & 31);
            int jb = 16 * s + 8 * (l >> 5);
            union { short8 v; unsigned short u[8]; } fr;
#pragma unroll
            for (int e = 0; e < 8; ++e)
                fr.u[e] = f2bf(x_lds[(jb + e) * BT + c]);
            bpack[f] = fr.v;
        }

        // ---- acc: g0 carries x_old + W0 for both groups; g1 pure partial ----
        f32x16 acc0, acc1;
        if (g == 0){
#pragma unroll
            for (int r = 0; r < 16; ++r){
                int d = 32 * t + (r & 3) + 8 * (r >> 2) + 4 * hi;
                acc0[r] = x_lds[d * BT + ln]      + w0_lds[d];
                acc1[r] = x_lds[d * BT + 32 + ln] + w0_lds[d];
            }
        } else {
#pragma unroll
            for (int r = 0; r < 16; ++r){ acc0[r] = 0.f; acc1[r] = 0.f; }
        }

        __syncthreads();                       // (B) bpack visible

        // pair p: rows (p,127-p), chains C_A=8-BK (x2 groups), C_B=1+BK (x2).
        // Uniform 9-slice prefetch; g1's last prefetch = linear row + pad.
#define PAIRS(BK)                                                               \
        _Pragma("unroll 2")                                                     \
        for (int q = 0; q < 16; ++q){                                           \
            const int cur = q & 1, nxt = cur ^ 1;                               \
            _Pragma("unroll")                                                   \
            for (int s = 0; s < 9; ++s) abuf[nxt][s] = ap[s * 64];              \
            ap += 9 * 64;                                                       \
            const int p = 16 * (BK) + q;                                        \
            float s0a = x_lds[p * BT + ln];                                     \
            float s0b = x_lds[p * BT + 32 + ln];                                \
            float s1a = x_lds[(127 - p) * BT + ln];                             \
            float s1b = x_lds[(127 - p) * BT + 32 + ln];                        \
            f32x16 Y0, Y1;                                                      \
            _Pragma("unroll")                                                   \
            for (int s = 0; s < 8 - (BK); ++s){                                 \
                short8 bq0 = bpack[((BK) + s) * 64 + lane];                     \
                short8 bq1 = bpack[512 + ((BK) + s) * 64 + lane];               \
                Y0 = __builtin_amdgcn_mfma_f32_32x32x16_bf16(abuf[cur][s], bq0, s ? Y0 : zero16, 0, 0, 0); \
                Y1 = __builtin_amdgcn_mfma_f32_32x32x16_bf16(abuf[cur][s], bq1, s ? Y1 : zero16, 0, 0, 0); \
            }                                                                   \
            acc0 += s0a * Y0;                                                   \
            acc1 += s0b * Y1;                                                   \
            f32x16 Z0, Z1;                                                      \
            _Pragma("unroll")                                                   \
            for (int s = 0; s < 1 + (BK); ++s){                                 \
                short8 bq0 = bpack[(7 - (BK) + s) * 64 + lane];                 \
                short8 bq1 = bpack[512 + (7 - (BK) + s) * 64 + lane];           \
                Z0 = __builtin_amdgcn_mfma_f32_32x32x16_bf16(abuf[cur][8 - (BK) + s], bq0, s ? Z0 : zero16, 0, 0, 0); \
                Z1 = __builtin_amdgcn_mfma_f32_32x32x16_bf16(abuf[cur][8 - (BK) + s], bq1, s ? Z1 : zero16, 0, 0, 0); \
            }                                                                   \
            acc0 += s1a * Z0;                                                   \
            acc1 += s1b * Z1;                                                   \
        }

        if (g == 0){
            PAIRS(0) PAIRS(1)
            // trailing prefetch read pairs 32.. (in-bounds, discarded)
        } else {
            PAIRS(2) PAIRS(3)
            // linear (W1) row, scale 1; abuf[0] holds slices 576..583
            f32x16 Y0, Y1;
#pragma unroll
            for (int s = 0; s < 8; ++s){
                short8 bq0 = bpack[s * 64 + lane];
                short8 bq1 = bpack[512 + s * 64 + lane];
                Y0 = __builtin_amdgcn_mfma_f32_32x32x16_bf16(abuf[0][s], bq0, s ? Y0 : zero16, 0, 0, 0);
                Y1 = __builtin_amdgcn_mfma_f32_32x32x16_bf16(abuf[0][s], bq1, s ? Y1 : zero16, 0, 0, 0);
            }
            acc0 += Y0;
            acc1 += Y1;
            // publish K-half partials
#pragma unroll
            for (int r = 0; r < 16; ++r){
                sc_lds[0][(t * 64 + lane) * 17 + r] = acc0[r];
                sc_lds[1][(t * 64 + lane) * 17 + r] = acc1[r];
            }
        }
#undef PAIRS

        __syncthreads();                       // (C) reads done + scratch visible
        if (g == 0){
#pragma unroll
            for (int r = 0; r < 16; ++r){
                acc0[r] += sc_lds[0][(t * 64 + lane) * 17 + r];
                acc1[r] += sc_lds[1][(t * 64 + lane) * 17 + r];
            }
            if (step < NSTEPS - 1){
#pragma unroll
                for (int r = 0; r < 16; ++r){
                    int d = 32 * t + (r & 3) + 8 * (r >> 2) + 4 * hi;
                    x_lds[d * BT + ln]      = acc0[r];
                    x_lds[d * BT + 32 + ln] = acc1[r];
                }
            } else if (t == 3 && hi == 0){
                // out dims 120..123 -> tile 3, regs 12..15 @ hi==0
                *(float4*)(out + (size_t)(b0 + ln) * 4) =
                    make_float4(acc0[12], acc0[13], acc0[14], acc0[15]);
                *(float4*)(out + (size_t)(b0 + 32 + ln) * 4) =
                    make_float4(acc1[12], acc1[13], acc1[14], acc1[15]);
            }
        }
        // next iteration's barrier (A) orders g0's x write vs g1's next reads
    }
}

extern "C" void kernel_launch(void* const* d_in, const int* in_sizes, int n_in,
                              void* d_out, int out_size, void* d_ws, size_t ws_size,
                              hipStream_t stream)
{
    const float* X  = (const float*)d_in[0];
    const float* W  = (const float*)d_in[1];
    const float* ti = (const float*)d_in[2];
    const float* li = (const float*)d_in[3];
    float* out      = (float*)d_out;
    short8* A       = (short8*)d_ws;           // 4*585*64*16 B = 2.40 MB

    const int ntotal = 4 * 130 * 8 * 64;
    prep_kernel<<<(ntotal + 255) / 256, 256, 0, stream>>>(W, A);
    taylor_kernel<<<BATCH / BT, 512, 0, stream>>>(X, W, ti, li, A, out);
}

// Round 9
// 325.120 us; speedup vs baseline: 1.2772x; 1.1282x over previous
//
#include <hip/hip_runtime.h>
#include <hip/hip_bf16.h>

// TaylorMap, symmetric-packed quadratic, uniform-9 pair stream.
// R9: per-BK-block register-cached B (both col-groups) + single rotating
// A buffer with per-register reload pipelining.
// R8 post-mortem: B was re-read from LDS once per MFMA (56k cyc/step/CU >
// MFMA pipe 38k). All 16 pairs of a PAIRS(BK) block use the same B slices
// (BK..7), so cache them in regs (2*(8-BK) <= 16 frags = 64 VGPR, 4 reloads
// per step). Pays the register bill by dropping abuf[2][9] -> abuf[9]:
// abuf[s] is reloaded for the NEXT pair right after the two MFMAs consuming
// it issue; ~500 cyc of remaining MFMA issue hides the load latency.
// Arch regs ~119 <= 128 (R6-proven shape). LDS kept 84.5 KB -> 1 block/CU
// -> compiler's LDS-derived occupancy gives the 256-unified-reg cap (R3 trap
// can't fire). A stream read once per CU per step; stream layout unchanged.

#define DSTATE 128
#define BATCH  16384
#define NSTEPS 7
#define BT     64
#define NSL    585          // slices per d-tile: 64*9 pair + 8 linear + 1 pad

typedef __attribute__((ext_vector_type(8)))  short  short8;   // 8 bf16 = 4 VGPRs
typedef __attribute__((ext_vector_type(16))) float  f32x16;   // MFMA 32x32 C/D

__device__ __forceinline__ unsigned short f2bf(float f){
    unsigned int u = __float_as_uint(f);
    u += 0x7fff + ((u >> 16) & 1);          // RNE
    return (unsigned short)(u >> 16);
}

// Pack symmetric-folded W into bf16 MFMA-A fragments, uniform-9 pair stream.
// Pair p at positions 9p..9p+8: first 8-(p>>4) slices are row p (j-blocks
// p>>4..7), remaining 1+(p>>4) are row 127-p (j-blocks 7-(p>>4)..7).
// Fragment layout: A[m][k], m=lane&31 -> d=32t+m, k=(lane>>5)*8+e -> j=16*s+k.
__global__ void prep_kernel(const float* __restrict__ W, short8* __restrict__ A){
    int gid = blockIdx.x * 256 + threadIdx.x;
    const int ntotal = 4 * 130 * 8 * 64;
    if (gid >= ntotal) return;
    int lane = gid & 63; int r = gid >> 6;
    int s = r & 7;  r >>= 3;
    int row = r % 130;
    int t   = r / 130;
    int d  = t * 32 + (lane & 31);
    int kb = (lane >> 5) * 8;
    int dst;
    bool zero = false;
    if (row < 64){
        int sl = row >> 4;
        if (s < sl) return;
        dst = t * NSL + 9 * row + (s - sl);
    } else if (row < 128){
        int p  = 127 - row;
        int sl = row >> 4;
        if (s < sl) return;
        int ca = 8 - (p >> 4);
        dst = t * NSL + 9 * p + ca + (s - sl);
    } else if (row == 128){
        dst = t * NSL + 576 + s;               // linear (W1) row
    } else {
        if (s) return;                         // zero pad slice
        dst = t * NSL + 584;
        zero = true;
    }
    union { short8 v; unsigned short u[8]; } fr;
#pragma unroll
    for (int e = 0; e < 8; ++e){
        int j = s * 16 + kb + e;
        float v;
        if (zero) v = 0.0f;
        else if (row < 128){
            if      (j < row)  v = 0.0f;
            else if (j == row) v = W[(129 + 128 * row + j) * 128 + d];
            else               v = W[(129 + 128 * row + j) * 128 + d]
                                 + W[(129 + 128 * j + row) * 128 + d];
        } else {
            v = W[(1 + j) * 128 + d];
        }
        fr.u[e] = f2bf(v);
    }
    A[(size_t)dst * 64 + lane] = fr.v;
}

__global__ __launch_bounds__(512)
void taylor_kernel(const float* __restrict__ X, const float* __restrict__ W,
                   const float* __restrict__ tini, const float* __restrict__ lini,
                   const short8* __restrict__ A, float* __restrict__ out)
{
    __shared__ float  x_lds[DSTATE * BT];      // fp32 master state [d][b], 32 KB
    __shared__ float  w0_lds[DSTATE];
    __shared__ short8 bpack[2 * 8 * 64];       // B frags, 2 groups x 8 slices, 16 KB
    __shared__ float  sc_lds[2][4 * 64 * 17];  // K-merge scratch, 34.8 KB

    const int tid  = threadIdx.x;
    const int lane = tid & 63;
    const int w    = tid >> 6;
    const int t    = w & 3;                    // d-tile
    const int g    = w >> 2;                   // K-half (pairs 0..31 / 32..63+lin)
    const int ln   = lane & 31;
    const int hi   = lane >> 5;
    const int b0   = blockIdx.x * BT;

    // ---- init x0 = [X | t_init | l_init] ----
#pragma unroll
    for (int it = 0; it < 16; ++it){
        int entry = tid + it * 512;            // entry = b*128 + d
        int b = entry >> 7, d = entry & 127;
        float v;
        if      (d < 120) v = X[(b0 + b) * 120 + d];
        else if (d < 124) v = tini[d - 120];
        else              v = lini[d - 124];
        x_lds[d * BT + b] = v;
    }
    if (tid < DSTATE) w0_lds[tid] = W[tid];

    // wave's half-stream base: g0 -> slice 0, g1 -> slice 288 (pair 32)
    const short8* const Aw = A + ((size_t)t * NSL + (size_t)g * 288) * 64 + lane;
    const f32x16 zero16 = {};                  // persistent zero C-operand

#pragma unroll 1
    for (int step = 0; step < NSTEPS; ++step){
        __syncthreads();                       // (A) x_lds stable

        // ---- prime A stream: pair 0 of this wave's half ----
        const short8* ap = Aw;
        short8 abuf[9];
#pragma unroll
        for (int s = 0; s < 9; ++s) abuf[s] = ap[s * 64];
        ap += 9 * 64;                          // reloads during pair q read pair q+1

        // ---- build bpack (1024 frags, 2 per thread) while loads fly ----
#pragma unroll
        for (int f0 = 0; f0 < 2; ++f0){
            int f  = tid + f0 * 512;
            int gg = f >> 9, s = (f >> 6) & 7, l = f & 63;
            int c  = gg * 32 + (l & 31);
            int jb = 16 * s + 8 * (l >> 5);
            union { short8 v; unsigned short u[8]; } fr;
#pragma unroll
            for (int e = 0; e < 8; ++e)
                fr.u[e] = f2bf(x_lds[(jb + e) * BT + c]);
            bpack[f] = fr.v;
        }

        // ---- acc: g0 carries x_old + W0 for both groups; g1 pure partial ----
        f32x16 acc0, acc1;
        if (g == 0){
#pragma unroll
            for (int r = 0; r < 16; ++r){
                int d = 32 * t + (r & 3) + 8 * (r >> 2) + 4 * hi;
                acc0[r] = x_lds[d * BT + ln]      + w0_lds[d];
                acc1[r] = x_lds[d * BT + 32 + ln] + w0_lds[d];
            }
        } else {
#pragma unroll
            for (int r = 0; r < 16; ++r){ acc0[r] = 0.f; acc1[r] = 0.f; }
        }

        __syncthreads();                       // (B) bpack visible

        short8 bfrag0[8], bfrag1[8];           // B reg-cache for current BK block

        // pair p=16*BK+q: rows (p,127-p). Y chain: slices BK..7 (abuf[0..7-BK],
        // bfrag idx s). Z chain: slices 7-BK..7 (abuf[8-BK..8], bfrag idx
        // 7-2BK+s). Each abuf[s] reloaded for the NEXT pair right after its
        // two consuming MFMAs issue -> load latency hidden by MFMA issue.
#define PAIRS(BK)                                                               \
        {                                                                       \
            _Pragma("unroll")                                                   \
            for (int s = 0; s < 8 - (BK); ++s){                                 \
                bfrag0[s] = bpack[((BK) + s) * 64 + lane];                      \
                bfrag1[s] = bpack[512 + ((BK) + s) * 64 + lane];                \
            }                                                                   \
            _Pragma("unroll 2")                                                 \
            for (int q = 0; q < 16; ++q){                                       \
                const int p = 16 * (BK) + q;                                    \
                float s0a = x_lds[p * BT + ln];                                 \
                float s0b = x_lds[p * BT + 32 + ln];                            \
                float s1a = x_lds[(127 - p) * BT + ln];                         \
                float s1b = x_lds[(127 - p) * BT + 32 + ln];                    \
                f32x16 Y0, Y1;                                                  \
                _Pragma("unroll")                                               \
                for (int s = 0; s < 8 - (BK); ++s){                             \
                    Y0 = __builtin_amdgcn_mfma_f32_32x32x16_bf16(abuf[s], bfrag0[s], s ? Y0 : zero16, 0, 0, 0); \
                    Y1 = __builtin_amdgcn_mfma_f32_32x32x16_bf16(abuf[s], bfrag1[s], s ? Y1 : zero16, 0, 0, 0); \
                    abuf[s] = ap[s * 64];                                       \
                }                                                               \
                acc0 += s0a * Y0;                                               \
                acc1 += s0b * Y1;                                               \
                f32x16 Z0, Z1;                                                  \
                _Pragma("unroll")                                               \
                for (int s = 0; s < 1 + (BK); ++s){                             \
                    Z0 = __builtin_amdgcn_mfma_f32_32x32x16_bf16(abuf[8 - (BK) + s], bfrag0[7 - 2 * (BK) + s], s ? Z0 : zero16, 0, 0, 0); \
                    Z1 = __builtin_amdgcn_mfma_f32_32x32x16_bf16(abuf[8 - (BK) + s], bfrag1[7 - 2 * (BK) + s], s ? Z1 : zero16, 0, 0, 0); \
                    abuf[8 - (BK) + s] = ap[(8 - (BK) + s) * 64];               \
                }                                                               \
                acc0 += s1a * Z0;                                               \
                acc1 += s1b * Z1;                                               \
                ap += 9 * 64;                                                   \
            }                                                                   \
        }

        if (g == 0){
            PAIRS(0) PAIRS(1)
            // q=15 reloads read pair 32 (in-bounds, discarded)
        } else {
            PAIRS(2) PAIRS(3)
            // q=15 reloads of PAIRS(3) loaded slices 576..584:
            // abuf[0..7] = linear (W1) row, abuf[8] = pad. Reload bfrag 0..7.
            f32x16 Y0, Y1;
#pragma unroll
            for (int s = 0; s < 8; ++s){
                bfrag0[s] = bpack[s * 64 + lane];
                bfrag1[s] = bpack[512 + s * 64 + lane];
            }
#pragma unroll
            for (int s = 0; s < 8; ++s){
                Y0 = __builtin_amdgcn_mfma_f32_32x32x16_bf16(abuf[s], bfrag0[s], s ? Y0 : zero16, 0, 0, 0);
                Y1 = __builtin_amdgcn_mfma_f32_32x32x16_bf16(abuf[s], bfrag1[s], s ? Y1 : zero16, 0, 0, 0);
            }
            acc0 += Y0;
            acc1 += Y1;
            // publish K-half partials
#pragma unroll
            for (int r = 0; r < 16; ++r){
                sc_lds[0][(t * 64 + lane) * 17 + r] = acc0[r];
                sc_lds[1][(t * 64 + lane) * 17 + r] = acc1[r];
            }
        }
#undef PAIRS

        __syncthreads();                       // (C) reads done + scratch visible
        if (g == 0){
#pragma unroll
            for (int r = 0; r < 16; ++r){
                acc0[r] += sc_lds[0][(t * 64 + lane) * 17 + r];
                acc1[r] += sc_lds[1][(t * 64 + lane) * 17 + r];
            }
            if (step < NSTEPS - 1){
#pragma unroll
                for (int r = 0; r < 16; ++r){
                    int d = 32 * t + (r & 3) + 8 * (r >> 2) + 4 * hi;
                    x_lds[d * BT + ln]      = acc0[r];
                    x_lds[d * BT + 32 + ln] = acc1[r];
                }
            } else if (t == 3 && hi == 0){
                // out dims 120..123 -> tile 3, regs 12..15 @ hi==0
                *(float4*)(out + (size_t)(b0 + ln) * 4) =
                    make_float4(acc0[12], acc0[13], acc0[14], acc0[15]);
                *(float4*)(out + (size_t)(b0 + 32 + ln) * 4) =
                    make_float4(acc1[12], acc1[13], acc1[14], acc1[15]);
            }
        }
        // next iteration's barrier (A) orders g0's x write vs g1's next reads
    }
}

extern "C" void kernel_launch(void* const* d_in, const int* in_sizes, int n_in,
                              void* d_out, int out_size, void* d_ws, size_t ws_size,
                              hipStream_t stream)
{
    const float* X  = (const float*)d_in[0];
    const float* W  = (const float*)d_in[1];
    const float* ti = (const float*)d_in[2];
    const float* li = (const float*)d_in[3];
    float* out      = (float*)d_out;
    short8* A       = (short8*)d_ws;           // 4*585*64*16 B = 2.40 MB

    const int ntotal = 4 * 130 * 8 * 64;
    prep_kernel<<<(ntotal + 255) / 256, 256, 0, stream>>>(W, A);
    taylor_kernel<<<BATCH / BT, 512, 0, stream>>>(X, W, ti, li, A, out);
}